// Round 5
// baseline (310.373 us; speedup 1.0000x reference)
//
#include <hip/hip_runtime.h>

#define N_NODES 50000
#define D 64

typedef __attribute__((ext_vector_type(4))) float f4;
typedef __attribute__((ext_vector_type(4))) unsigned uv4;
typedef __attribute__((ext_vector_type(4))) unsigned short us4;

// f32 -> bf16 round-to-nearest-even
static __device__ __forceinline__ unsigned short f2bf(float f) {
    unsigned u = __builtin_bit_cast(unsigned, f);
    unsigned r = (u + 0x7fffu + ((u >> 16) & 1u)) >> 16;
    return (unsigned short)r;
}
static __device__ __forceinline__ float bf2f(unsigned short b) {
    return __builtin_bit_cast(float, (unsigned)b << 16);
}

// int64-vs-int32 probe, inlined per wave: for int64 edge_index with ids<2^31,
// the first 32 odd 32-bit words (high halves of src) are all zero; for int32
// they are random src values (P(all zero) ~ 0). One broadcast line from L2.
static __device__ __forceinline__ int detect_is64(const unsigned* __restrict__ ei32) {
    int lane = threadIdx.x & 63;
    unsigned v = (lane < 32) ? ei32[2 * lane + 1] : 0u;
    return (__ballot(v != 0u) == 0ull) ? 1 : 0;
}

// ---------------------------------------------------------------------------
// 0. x (f32 [N][64]) -> two bf16 planes [N][32] (each 3.2MB: fits per-XCD L2)
// ---------------------------------------------------------------------------
__global__ __launch_bounds__(256) void cvt_kernel(const float* __restrict__ x,
                                                  unsigned short* __restrict__ p0,
                                                  unsigned short* __restrict__ p1,
                                                  int total) {
    int i = (blockIdx.x * 256 + threadIdx.x) * 4;
    if (i + 3 < total) {
        f4 v = *(const f4*)&x[i];
        us4 o;
        o[0] = f2bf(v[0]); o[1] = f2bf(v[1]); o[2] = f2bf(v[2]); o[3] = f2bf(v[3]);
        int node = i >> 6, f = i & 63;
        unsigned short* p = (f < 32) ? p0 : p1;
        *(us4*)&p[(size_t)node * 32 + (f & 31)] = o;
    } else {
        for (int j = i; j < total; ++j) {
            int node = j >> 6, f = j & 63;
            unsigned short* p = (f < 32) ? p0 : p1;
            p[(size_t)node * 32 + (f & 31)] = f2bf(x[j]);
        }
    }
}

// ---------------------------------------------------------------------------
// 1. histogram of dst — 4 edges/thread, uint4 loads
// ---------------------------------------------------------------------------
__global__ __launch_bounds__(256) void hist_kernel(const unsigned* __restrict__ ei32,
                                                   int E, int* __restrict__ cnt) {
    int is64 = detect_is64(ei32);
    int base = (blockIdx.x * 256 + threadIdx.x) * 4;
    if (base >= E) return;
    if (base + 3 < E && (E & 3) == 0) {
        int d0, d1, d2, d3;
        if (is64) {
            uv4 a = *(const uv4*)&ei32[2 * (E + base)];
            uv4 b = *(const uv4*)&ei32[2 * (E + base) + 4];
            d0 = (int)a[0]; d1 = (int)a[2]; d2 = (int)b[0]; d3 = (int)b[2];
        } else {
            uv4 a = *(const uv4*)&ei32[E + base];
            d0 = (int)a[0]; d1 = (int)a[1]; d2 = (int)a[2]; d3 = (int)a[3];
        }
        atomicAdd(&cnt[d0], 1); atomicAdd(&cnt[d1], 1);
        atomicAdd(&cnt[d2], 1); atomicAdd(&cnt[d3], 1);
    } else {
        for (int e = base; e < E && e < base + 4; ++e) {
            int d = is64 ? (int)ei32[2 * (E + e)] : (int)ei32[E + e];
            atomicAdd(&cnt[d], 1);
        }
    }
}

// ---------------------------------------------------------------------------
// 2. two-kernel exclusive scan (nb <= 256; nb = 196 here)
// ---------------------------------------------------------------------------
__global__ __launch_bounds__(256) void scan_partial(const int* __restrict__ cnt,
                                                    int* __restrict__ bsum, int n) {
    __shared__ int ws4[4];
    int i = blockIdx.x * 256 + threadIdx.x;
    int v = (i < n) ? cnt[i] : 0;
#pragma unroll
    for (int off = 1; off < 64; off <<= 1) v += __shfl_xor(v, off);
    int wave = threadIdx.x >> 6, lane = threadIdx.x & 63;
    if (lane == 0) ws4[wave] = v;
    __syncthreads();
    if (threadIdx.x == 0) bsum[blockIdx.x] = ws4[0] + ws4[1] + ws4[2] + ws4[3];
}

__global__ __launch_bounds__(256) void scan_final(const int* __restrict__ cnt,
                                                  const int* __restrict__ bsum,
                                                  int* __restrict__ rp,
                                                  int* __restrict__ cursor, int n, int nb) {
    __shared__ int sb[256];
    __shared__ int sOff[4];
    int tid = threadIdx.x;
    int pb = (tid < blockIdx.x && tid < nb) ? bsum[tid] : 0;
#pragma unroll
    for (int off = 1; off < 64; off <<= 1) pb += __shfl_xor(pb, off);
    int wv = tid >> 6, ln = tid & 63;
    if (ln == 0) sOff[wv] = pb;
    __syncthreads();
    int boff = sOff[0] + sOff[1] + sOff[2] + sOff[3];

    int i = blockIdx.x * 256 + tid;
    int v = (i < n) ? cnt[i] : 0;
    sb[tid] = v;
    __syncthreads();
    for (int off = 1; off < 256; off <<= 1) {
        int t = (tid >= off) ? sb[tid - off] : 0;
        __syncthreads();
        sb[tid] += t;
        __syncthreads();
    }
    if (i < n) {
        int e = boff + sb[tid] - v;
        rp[i] = e;
        cursor[i] = e;
    }
    if (blockIdx.x == gridDim.x - 1 && tid == 255) rp[n] = boff + sb[255];
}

// ---------------------------------------------------------------------------
// 3. scatter src (ushort) into CSR order — 4 edges/thread
// ---------------------------------------------------------------------------
__global__ __launch_bounds__(256) void scatter_kernel(const unsigned* __restrict__ ei32,
                                                      int E, int* __restrict__ cursor,
                                                      unsigned short* __restrict__ ssrc) {
    int is64 = detect_is64(ei32);
    int base = (blockIdx.x * 256 + threadIdx.x) * 4;
    if (base >= E) return;
    if (base + 3 < E && (E & 3) == 0) {
        int s0, s1, s2, s3, d0, d1, d2, d3;
        if (is64) {
            uv4 sa = *(const uv4*)&ei32[2 * base];
            uv4 sbv = *(const uv4*)&ei32[2 * base + 4];
            uv4 da = *(const uv4*)&ei32[2 * (E + base)];
            uv4 db = *(const uv4*)&ei32[2 * (E + base) + 4];
            s0 = (int)sa[0]; s1 = (int)sa[2]; s2 = (int)sbv[0]; s3 = (int)sbv[2];
            d0 = (int)da[0]; d1 = (int)da[2]; d2 = (int)db[0]; d3 = (int)db[2];
        } else {
            uv4 sa = *(const uv4*)&ei32[base];
            uv4 da = *(const uv4*)&ei32[E + base];
            s0 = (int)sa[0]; s1 = (int)sa[1]; s2 = (int)sa[2]; s3 = (int)sa[3];
            d0 = (int)da[0]; d1 = (int)da[1]; d2 = (int)da[2]; d3 = (int)da[3];
        }
        int p0 = atomicAdd(&cursor[d0], 1);
        int p1 = atomicAdd(&cursor[d1], 1);
        int p2 = atomicAdd(&cursor[d2], 1);
        int p3 = atomicAdd(&cursor[d3], 1);
        ssrc[p0] = (unsigned short)s0;
        ssrc[p1] = (unsigned short)s1;
        ssrc[p2] = (unsigned short)s2;
        ssrc[p3] = (unsigned short)s3;
    } else {
        for (int e = base; e < E && e < base + 4; ++e) {
            int s = is64 ? (int)ei32[2 * e] : (int)ei32[e];
            int d = is64 ? (int)ei32[2 * (E + e)] : (int)ei32[E + e];
            int pos = atomicAdd(&cursor[d], 1);
            ssrc[pos] = (unsigned short)s;
        }
    }
}

// ---------------------------------------------------------------------------
// 4a. half-feature aggregation over one 3.2MB bf16 plane (L2-resident).
//     wave per node; lane = (r 0..15 edge slot, c 0..3 16B chunk) ->
//     16 edges per wave-instruction in flight. shfl_xor reduce over r.
// ---------------------------------------------------------------------------
__global__ __launch_bounds__(256) void agg_half(const unsigned short* __restrict__ plane,
                                                const int* __restrict__ rp,
                                                const unsigned short* __restrict__ ssrc,
                                                float* __restrict__ agg, int n, int hoff) {
    int gw = (blockIdx.x * 256 + threadIdx.x) >> 6;
    if (gw >= n) return;
    int lane = threadIdx.x & 63;
    int r = lane >> 2;   // edge slot 0..15
    int c = lane & 3;    // 16B chunk 0..3 (cols c*8 .. c*8+7)
    int beg = rp[gw], end = rp[gw + 1];
    float acc[8] = {0.f, 0.f, 0.f, 0.f, 0.f, 0.f, 0.f, 0.f};
    for (int e = beg + r; e < end; e += 16) {
        int s = ssrc[e];
        uv4 v = *(const uv4*)(plane + (size_t)s * 32 + c * 8);
#pragma unroll
        for (int q = 0; q < 4; ++q) {
            unsigned w = v[q];
            acc[2 * q]     += __builtin_bit_cast(float, w << 16);
            acc[2 * q + 1] += __builtin_bit_cast(float, w & 0xffff0000u);
        }
    }
#pragma unroll
    for (int j = 0; j < 8; ++j) {
        float t = acc[j];
        t += __shfl_xor(t, 4);
        t += __shfl_xor(t, 8);
        t += __shfl_xor(t, 16);
        t += __shfl_xor(t, 32);
        acc[j] = t;
    }
    if (r < 2) {
        int deg = end - beg;
        float inv = 1.0f / (float)(deg > 1 ? deg : 1);
        float* dst = &agg[(size_t)gw * 64 + hoff + c * 8 + r * 4];
        if (r == 0) {
            f4 o = {acc[0] * inv, acc[1] * inv, acc[2] * inv, acc[3] * inv};
            *(f4*)dst = o;
        } else {
            f4 o = {acc[4] * inv, acc[5] * inv, acc[6] * inv, acc[7] * inv};
            *(f4*)dst = o;
        }
    }
}

// ---------------------------------------------------------------------------
// 4b. linear: out[n][o] = agg[n].Wl[o] + x[n].Wr[o] + bl[o] (+relu)
//     lane o holds Wl[o], Wr[o] in VGPRs; per-node features broadcast via
//     v_readlane (VALU, no LDS pipe). x-side read from bf16 planes.
//     LAST: write f32 d_out; else: write bf16 planes for next layer.
// ---------------------------------------------------------------------------
template <bool RELU, bool LAST>
__global__ __launch_bounds__(256) void lin_kernel(const float* __restrict__ aggp,
                                                  const unsigned short* __restrict__ xp0,
                                                  const unsigned short* __restrict__ xp1,
                                                  const float* __restrict__ Wl,
                                                  const float* __restrict__ bl,
                                                  const float* __restrict__ Wr,
                                                  float* __restrict__ out,
                                                  unsigned short* __restrict__ ob0,
                                                  unsigned short* __restrict__ ob1, int n) {
    int lane = threadIdx.x & 63;
    f4 wl[16], wr[16];
#pragma unroll
    for (int k = 0; k < 16; ++k) {
        wl[k] = *(const f4*)&Wl[lane * 64 + k * 4];
        wr[k] = *(const f4*)&Wr[lane * 64 + k * 4];
    }
    float b = bl[lane];
    const unsigned short* xp = (lane < 32) ? xp0 : xp1;
    unsigned short* op = (lane < 32) ? ob0 : ob1;
    int col = lane & 31;
    int gw = (blockIdx.x * 256 + threadIdx.x) >> 6;
    int nw = gridDim.x * 4;
    for (int node = gw; node < n; node += nw) {
        int ai = __builtin_bit_cast(int, aggp[(size_t)node * 64 + lane]);
        int xi = (int)((unsigned)xp[(size_t)node * 32 + col] << 16);
        float accl0 = 0.f, accl1 = 0.f, accr0 = 0.f, accr1 = 0.f;
#pragma unroll
        for (int k = 0; k < 64; k += 2) {
            float a0 = __builtin_bit_cast(float, __builtin_amdgcn_readlane(ai, k));
            float x0 = __builtin_bit_cast(float, __builtin_amdgcn_readlane(xi, k));
            float a1 = __builtin_bit_cast(float, __builtin_amdgcn_readlane(ai, k + 1));
            float x1 = __builtin_bit_cast(float, __builtin_amdgcn_readlane(xi, k + 1));
            accl0 = fmaf(a0, wl[k >> 2][k & 3], accl0);
            accr0 = fmaf(x0, wr[k >> 2][k & 3], accr0);
            accl1 = fmaf(a1, wl[(k + 1) >> 2][(k + 1) & 3], accl1);
            accr1 = fmaf(x1, wr[(k + 1) >> 2][(k + 1) & 3], accr1);
        }
        float res = (accl0 + accl1) + (accr0 + accr1) + b;
        if (RELU) res = fmaxf(res, 0.f);
        if (LAST) {
            out[(size_t)node * 64 + lane] = res;
        } else {
            op[(size_t)node * 32 + col] = f2bf(res);
        }
    }
}

// ---------------------------------------------------------------------------
extern "C" void kernel_launch(void* const* d_in, const int* in_sizes, int n_in,
                              void* d_out, int out_size, void* d_ws, size_t ws_size,
                              hipStream_t stream) {
    const float* x      = (const float*)d_in[0];
    const unsigned* ei  = (const unsigned*)d_in[1];
    const float* Wl0    = (const float*)d_in[2];
    const float* bl0    = (const float*)d_in[3];
    const float* Wr0    = (const float*)d_in[4];
    const float* Wl1    = (const float*)d_in[5];
    const float* bl1    = (const float*)d_in[6];
    const float* Wr1    = (const float*)d_in[7];
    float* out          = (float*)d_out;

    const int N = N_NODES;
    const int E = in_sizes[1] / 2;
    const int NB = (N + 255) / 256;   // 196 scan blocks (<= 256 required)

    char* w = (char*)d_ws;
    auto take = [&](size_t bytes) {
        char* p = w;
        w += (bytes + 255) & ~(size_t)255;
        return p;
    };
    int*            cnt    = (int*)take((size_t)N * sizeof(int));
    int*            rp     = (int*)take((size_t)(N + 1) * sizeof(int));
    int*            cursor = (int*)take((size_t)N * sizeof(int));
    unsigned short* ssrc   = (unsigned short*)take((size_t)E * sizeof(unsigned short));
    int*            bsum   = (int*)take((size_t)NB * sizeof(int));
    float*          agg    = (float*)take((size_t)N * D * sizeof(float));
    unsigned short* xp0    = (unsigned short*)take((size_t)N * 32 * sizeof(unsigned short));
    unsigned short* xp1    = (unsigned short*)take((size_t)N * 32 * sizeof(unsigned short));
    unsigned short* hp0    = (unsigned short*)take((size_t)N * 32 * sizeof(unsigned short));
    unsigned short* hp1    = (unsigned short*)take((size_t)N * 32 * sizeof(unsigned short));

    hipMemsetAsync(cnt, 0, (size_t)N * sizeof(int), stream);
    cvt_kernel<<<(N * D / 4 + 255) / 256, 256, 0, stream>>>(x, xp0, xp1, N * D);
    hist_kernel<<<(E / 4 + 255) / 256, 256, 0, stream>>>(ei, E, cnt);
    scan_partial<<<NB, 256, 0, stream>>>(cnt, bsum, N);
    scan_final<<<NB, 256, 0, stream>>>(cnt, bsum, rp, cursor, N, NB);
    scatter_kernel<<<(E / 4 + 255) / 256, 256, 0, stream>>>(ei, E, cursor, ssrc);

    int aggBlocks = (N * 64 + 255) / 256;   // one wave per node
    // layer 1
    agg_half<<<aggBlocks, 256, 0, stream>>>(xp0, rp, ssrc, agg, N, 0);
    agg_half<<<aggBlocks, 256, 0, stream>>>(xp1, rp, ssrc, agg, N, 32);
    lin_kernel<true, false><<<1024, 256, 0, stream>>>(agg, xp0, xp1, Wl0, bl0, Wr0,
                                                      nullptr, hp0, hp1, N);
    // layer 2
    agg_half<<<aggBlocks, 256, 0, stream>>>(hp0, rp, ssrc, agg, N, 0);
    agg_half<<<aggBlocks, 256, 0, stream>>>(hp1, rp, ssrc, agg, N, 32);
    lin_kernel<false, true><<<1024, 256, 0, stream>>>(agg, hp0, hp1, Wl1, bl1, Wr1,
                                                      out, nullptr, nullptr, N);
}

// Round 6
// 270.754 us; speedup vs baseline: 1.1463x; 1.1463x over previous
//
#include <hip/hip_runtime.h>

#define N_NODES 50000
#define D 64
#define BKT_SHIFT 10
#define BKT_NODES 1024
#define NBKT ((N_NODES + BKT_NODES - 1) / BKT_NODES)   // 49 buckets

typedef __attribute__((ext_vector_type(4))) float f4;
typedef __attribute__((ext_vector_type(4))) unsigned uv4;
typedef __attribute__((ext_vector_type(4))) unsigned short us4;

// f32 -> bf16 round-to-nearest-even
static __device__ __forceinline__ unsigned short f2bf(float f) {
    unsigned u = __builtin_bit_cast(unsigned, f);
    unsigned r = (u + 0x7fffu + ((u >> 16) & 1u)) >> 16;
    return (unsigned short)r;
}

// int64-vs-int32 probe, inlined per wave: for int64 edge_index with ids<2^31,
// the first 32 odd 32-bit words (high halves of src) are all zero.
static __device__ __forceinline__ int detect_is64(const unsigned* __restrict__ ei32) {
    int lane = threadIdx.x & 63;
    unsigned v = (lane < 32) ? ei32[2 * lane + 1] : 0u;
    return (__ballot(v != 0u) == 0ull) ? 1 : 0;
}

// load 4 edges (src,dst) starting at edge `base`; returns count (<=4)
static __device__ __forceinline__ int load_edges4(const unsigned* __restrict__ ei32,
                                                  int is64, int E, int base,
                                                  int* s, int* d) {
    if (base + 3 < E) {
        if (is64) {
            uv4 sa = *(const uv4*)&ei32[2 * base];
            uv4 sb = *(const uv4*)&ei32[2 * base + 4];
            uv4 da = *(const uv4*)&ei32[2 * (E + base)];
            uv4 db = *(const uv4*)&ei32[2 * (E + base) + 4];
            s[0] = (int)sa[0]; s[1] = (int)sa[2]; s[2] = (int)sb[0]; s[3] = (int)sb[2];
            d[0] = (int)da[0]; d[1] = (int)da[2]; d[2] = (int)db[0]; d[3] = (int)db[2];
        } else {
            uv4 sa = *(const uv4*)&ei32[base];
            uv4 da = *(const uv4*)&ei32[E + base];
            s[0] = (int)sa[0]; s[1] = (int)sa[1]; s[2] = (int)sa[2]; s[3] = (int)sa[3];
            d[0] = (int)da[0]; d[1] = (int)da[1]; d[2] = (int)da[2]; d[3] = (int)da[3];
        }
        return 4;
    }
    int c = 0;
    for (int e = base; e < E && e < base + 4; ++e, ++c) {
        s[c] = is64 ? (int)ei32[2 * e] : (int)ei32[e];
        d[c] = is64 ? (int)ei32[2 * (E + e)] : (int)ei32[E + e];
    }
    return c;
}

// ---------------------------------------------------------------------------
// 0. x (f32 [N][64]) -> bf16 table [N][64]
// ---------------------------------------------------------------------------
__global__ __launch_bounds__(256) void cvt_kernel(const float* __restrict__ x,
                                                  unsigned short* __restrict__ xb, int total) {
    int i = (blockIdx.x * 256 + threadIdx.x) * 4;
    if (i + 3 < total) {
        f4 v = *(const f4*)&x[i];
        us4 o;
        o[0] = f2bf(v[0]); o[1] = f2bf(v[1]); o[2] = f2bf(v[2]); o[3] = f2bf(v[3]);
        *(us4*)&xb[i] = o;
    } else {
        for (int j = i; j < total; ++j) xb[j] = f2bf(x[j]);
    }
}

// ---------------------------------------------------------------------------
// 1. bucket-level histogram of dst (49 buckets of 1024 nodes)
// ---------------------------------------------------------------------------
__global__ __launch_bounds__(256) void bucket_hist(const unsigned* __restrict__ ei32,
                                                   int E, int* __restrict__ gcnt) {
    __shared__ int bc[NBKT];
    int tid = threadIdx.x;
    for (int j = tid; j < NBKT; j += 256) bc[j] = 0;
    __syncthreads();
    int is64 = detect_is64(ei32);
    int base = (blockIdx.x * 256 + tid) * 4;
    if (base < E) {
        int s[4], d[4];
        int c = load_edges4(ei32, is64, E, base, s, d);
        for (int t = 0; t < c; ++t) atomicAdd(&bc[d[t] >> BKT_SHIFT], 1);
    }
    __syncthreads();
    for (int j = tid; j < NBKT; j += 256)
        if (bc[j]) atomicAdd(&gcnt[j], bc[j]);
}

// ---------------------------------------------------------------------------
// 2. one-wave exclusive scan of bucket counts -> bases + bin cursors
// ---------------------------------------------------------------------------
__global__ void bucket_scan(const int* __restrict__ gcnt,
                            int* __restrict__ bbase, int* __restrict__ gcur) {
    int lane = threadIdx.x;   // 64 threads
    int c = (lane < NBKT) ? gcnt[lane] : 0;
    int incl = c;
#pragma unroll
    for (int off = 1; off < 64; off <<= 1) {
        int t = __shfl_up(incl, off);
        if (lane >= off) incl += t;
    }
    if (lane < NBKT) { bbase[lane] = incl - c; gcur[lane] = incl - c; }
    if (lane == NBKT - 1) bbase[NBKT] = incl;
}

// ---------------------------------------------------------------------------
// 3. bin: group edges by bucket; per-block LDS count -> reserve chunk via one
//    global atomic per bucket -> write packed (dstLocal<<16 | src) into
//    block-private chunks (no cross-block cache-line sharing).
// ---------------------------------------------------------------------------
__global__ __launch_bounds__(256) void bin_kernel(const unsigned* __restrict__ ei32,
                                                  int E, int* __restrict__ gcur,
                                                  unsigned* __restrict__ binned) {
    __shared__ int bc[NBKT];
    __shared__ int boff[NBKT];
    int tid = threadIdx.x;
    for (int j = tid; j < NBKT; j += 256) bc[j] = 0;
    __syncthreads();
    int is64 = detect_is64(ei32);
    int base = (blockIdx.x * 256 + tid) * 4;
    int s[4], d[4];
    int c = 0;
    if (base < E) c = load_edges4(ei32, is64, E, base, s, d);
    for (int t = 0; t < c; ++t) atomicAdd(&bc[d[t] >> BKT_SHIFT], 1);
    __syncthreads();
    for (int j = tid; j < NBKT; j += 256) {
        int v = bc[j];
        boff[j] = v ? atomicAdd(&gcur[j], v) : 0;
        bc[j] = 0;
    }
    __syncthreads();
    for (int t = 0; t < c; ++t) {
        int b = d[t] >> BKT_SHIFT;
        int pos = boff[b] + atomicAdd(&bc[b], 1);
        binned[pos] = ((unsigned)(d[t] & (BKT_NODES - 1)) << 16) | (unsigned)s[t];
    }
}

// ---------------------------------------------------------------------------
// 4. build: one block per bucket. LDS node histogram (1024), LDS scan,
//    write rp, then scatter ssrc (ushort) — random 2B writes confined to the
//    bucket's ~32KB CSR window (single block -> single XCD L2, absorbed).
// ---------------------------------------------------------------------------
__global__ __launch_bounds__(256) void build_kernel(const unsigned* __restrict__ binned,
                                                    const int* __restrict__ bbase,
                                                    int* __restrict__ rp,
                                                    unsigned short* __restrict__ ssrc, int n) {
    __shared__ int nc[BKT_NODES];
    __shared__ int wpart[4];
    int b = blockIdx.x;
    int tid = threadIdx.x;
    int ebase = bbase[b], eend = bbase[b + 1];
    for (int j = tid; j < BKT_NODES; j += 256) nc[j] = 0;
    __syncthreads();
    for (int i = ebase + tid; i < eend; i += 256)
        atomicAdd(&nc[binned[i] >> 16], 1);
    __syncthreads();
    // exclusive scan of nc[1024]: each thread owns 4 consecutive entries
    int v[4]; int ts = 0;
#pragma unroll
    for (int i = 0; i < 4; ++i) { v[i] = nc[tid * 4 + i]; ts += v[i]; }
    int lane = tid & 63, wv = tid >> 6;
    int incl = ts;
#pragma unroll
    for (int off = 1; off < 64; off <<= 1) {
        int t = __shfl_up(incl, off);
        if (lane >= off) incl += t;
    }
    if (lane == 63) wpart[wv] = incl;
    __syncthreads();
    int wb = 0;
    for (int w2 = 0; w2 < wv; ++w2) wb += wpart[w2];
    int run = ebase + wb + incl - ts;   // exclusive global position
#pragma unroll
    for (int i = 0; i < 4; ++i) {
        int node = b * BKT_NODES + tid * 4 + i;
        nc[tid * 4 + i] = run;          // becomes the scatter cursor
        if (node < n) rp[node] = run;
        run += v[i];
    }
    if (b == NBKT - 1 && tid == 0) rp[n] = eend;
    __syncthreads();
    for (int i = ebase + tid; i < eend; i += 256) {
        unsigned u = binned[i];
        int pos = atomicAdd(&nc[u >> 16], 1);
        ssrc[pos] = (unsigned short)(u & 0xffffu);
    }
}

// ---------------------------------------------------------------------------
// 5. aggregation (bf16 rows [N][64]): wave per node.
//    lane = (slot r 0..7, chunk c 0..7); 16B bf16x8 load per lane -> 8 edges
//    per instruction, x2 unroll = 16 outstanding. shfl_xor reduce over r.
// ---------------------------------------------------------------------------
__global__ __launch_bounds__(256) void agg_kernel(const unsigned short* __restrict__ xb,
                                                  const int* __restrict__ rp,
                                                  const unsigned short* __restrict__ ssrc,
                                                  float* __restrict__ agg, int n) {
    int gw = (blockIdx.x * 256 + threadIdx.x) >> 6;
    if (gw >= n) return;
    int lane = threadIdx.x & 63;
    int r = lane >> 3;   // edge slot 0..7
    int c = lane & 7;    // bf16x8 chunk 0..7
    int beg = rp[gw], end = rp[gw + 1];
    float acc[8] = {0.f, 0.f, 0.f, 0.f, 0.f, 0.f, 0.f, 0.f};
    int e = beg + r;
    for (; e + 8 < end; e += 16) {
        int s0 = ssrc[e];
        int s1 = ssrc[e + 8];
        uv4 v0 = *(const uv4*)(xb + (size_t)s0 * 64 + c * 8);
        uv4 v1 = *(const uv4*)(xb + (size_t)s1 * 64 + c * 8);
#pragma unroll
        for (int q = 0; q < 4; ++q) {
            unsigned w0 = v0[q], w1 = v1[q];
            acc[2 * q]     += __builtin_bit_cast(float, w0 << 16);
            acc[2 * q + 1] += __builtin_bit_cast(float, w0 & 0xffff0000u);
            acc[2 * q]     += __builtin_bit_cast(float, w1 << 16);
            acc[2 * q + 1] += __builtin_bit_cast(float, w1 & 0xffff0000u);
        }
    }
    if (e < end) {
        int s0 = ssrc[e];
        uv4 v0 = *(const uv4*)(xb + (size_t)s0 * 64 + c * 8);
#pragma unroll
        for (int q = 0; q < 4; ++q) {
            unsigned w0 = v0[q];
            acc[2 * q]     += __builtin_bit_cast(float, w0 << 16);
            acc[2 * q + 1] += __builtin_bit_cast(float, w0 & 0xffff0000u);
        }
    }
#pragma unroll
    for (int j = 0; j < 8; ++j) {
        float t = acc[j];
        t += __shfl_xor(t, 8);
        t += __shfl_xor(t, 16);
        t += __shfl_xor(t, 32);
        acc[j] = t;
    }
    if (r == 0) {
        int deg = end - beg;
        float inv = 1.0f / (float)(deg > 1 ? deg : 1);
        f4 o0 = {acc[0] * inv, acc[1] * inv, acc[2] * inv, acc[3] * inv};
        f4 o1 = {acc[4] * inv, acc[5] * inv, acc[6] * inv, acc[7] * inv};
        *(f4*)&agg[(size_t)gw * 64 + c * 8] = o0;
        *(f4*)&agg[(size_t)gw * 64 + c * 8 + 4] = o1;
    }
}

// ---------------------------------------------------------------------------
// 6. linear: out[n][o] = agg[n].Wl[o] + x[n].Wr[o] + bl[o] (+relu)
//    lane o holds Wl[o], Wr[o] in VGPRs; per-node features broadcast via
//    v_readlane (VALU->SGPR, no LDS pipe). x-side from the bf16 table.
// ---------------------------------------------------------------------------
template <bool RELU, bool LAST>
__global__ __launch_bounds__(256) void lin_kernel(const float* __restrict__ aggp,
                                                  const unsigned short* __restrict__ xb,
                                                  const float* __restrict__ Wl,
                                                  const float* __restrict__ bl,
                                                  const float* __restrict__ Wr,
                                                  float* __restrict__ out,
                                                  unsigned short* __restrict__ ob, int n) {
    int lane = threadIdx.x & 63;
    f4 wl[16], wr[16];
#pragma unroll
    for (int k = 0; k < 16; ++k) {
        wl[k] = *(const f4*)&Wl[lane * 64 + k * 4];
        wr[k] = *(const f4*)&Wr[lane * 64 + k * 4];
    }
    float b = bl[lane];
    int gw = (blockIdx.x * 256 + threadIdx.x) >> 6;
    int nw = gridDim.x * 4;
    for (int node = gw; node < n; node += nw) {
        int ai = __builtin_bit_cast(int, aggp[(size_t)node * 64 + lane]);
        int xi = (int)((unsigned)xb[(size_t)node * 64 + lane] << 16);
        float accl0 = 0.f, accl1 = 0.f, accr0 = 0.f, accr1 = 0.f;
#pragma unroll
        for (int k = 0; k < 64; k += 2) {
            float a0 = __builtin_bit_cast(float, __builtin_amdgcn_readlane(ai, k));
            float x0 = __builtin_bit_cast(float, __builtin_amdgcn_readlane(xi, k));
            float a1 = __builtin_bit_cast(float, __builtin_amdgcn_readlane(ai, k + 1));
            float x1 = __builtin_bit_cast(float, __builtin_amdgcn_readlane(xi, k + 1));
            accl0 = fmaf(a0, wl[k >> 2][k & 3], accl0);
            accr0 = fmaf(x0, wr[k >> 2][k & 3], accr0);
            accl1 = fmaf(a1, wl[(k + 1) >> 2][(k + 1) & 3], accl1);
            accr1 = fmaf(x1, wr[(k + 1) >> 2][(k + 1) & 3], accr1);
        }
        float res = (accl0 + accl1) + (accr0 + accr1) + b;
        if (RELU) res = fmaxf(res, 0.f);
        if (LAST) out[(size_t)node * 64 + lane] = res;
        else      ob[(size_t)node * 64 + lane] = f2bf(res);
    }
}

// ---------------------------------------------------------------------------
extern "C" void kernel_launch(void* const* d_in, const int* in_sizes, int n_in,
                              void* d_out, int out_size, void* d_ws, size_t ws_size,
                              hipStream_t stream) {
    const float* x      = (const float*)d_in[0];
    const unsigned* ei  = (const unsigned*)d_in[1];
    const float* Wl0    = (const float*)d_in[2];
    const float* bl0    = (const float*)d_in[3];
    const float* Wr0    = (const float*)d_in[4];
    const float* Wl1    = (const float*)d_in[5];
    const float* bl1    = (const float*)d_in[6];
    const float* Wr1    = (const float*)d_in[7];
    float* out          = (float*)d_out;

    const int N = N_NODES;
    const int E = in_sizes[1] / 2;

    char* w = (char*)d_ws;
    auto take = [&](size_t bytes) {
        char* p = w;
        w += (bytes + 255) & ~(size_t)255;
        return p;
    };
    int*            gcnt   = (int*)take((size_t)NBKT * sizeof(int));
    int*            bbase  = (int*)take((size_t)(NBKT + 1) * sizeof(int));
    int*            gcur   = (int*)take((size_t)NBKT * sizeof(int));
    unsigned*       binned = (unsigned*)take((size_t)E * sizeof(unsigned));
    int*            rp     = (int*)take((size_t)(N + 1) * sizeof(int));
    unsigned short* ssrc   = (unsigned short*)take((size_t)E * sizeof(unsigned short));
    float*          agg    = (float*)take((size_t)N * D * sizeof(float));
    unsigned short* xb     = (unsigned short*)take((size_t)N * D * sizeof(unsigned short));
    unsigned short* hb     = (unsigned short*)take((size_t)N * D * sizeof(unsigned short));

    hipMemsetAsync(gcnt, 0, (size_t)NBKT * sizeof(int), stream);
    cvt_kernel<<<(N * D / 4 + 255) / 256, 256, 0, stream>>>(x, xb, N * D);

    int edgeBlocks = (E + 1023) / 1024;   // 4 edges/thread
    bucket_hist<<<edgeBlocks, 256, 0, stream>>>(ei, E, gcnt);
    bucket_scan<<<1, 64, 0, stream>>>(gcnt, bbase, gcur);
    bin_kernel<<<edgeBlocks, 256, 0, stream>>>(ei, E, gcur, binned);
    build_kernel<<<NBKT, 256, 0, stream>>>(binned, bbase, rp, ssrc, N);

    int aggBlocks = (N * 64 + 255) / 256;   // one wave per node
    agg_kernel<<<aggBlocks, 256, 0, stream>>>(xb, rp, ssrc, agg, N);
    lin_kernel<true, false><<<1024, 256, 0, stream>>>(agg, xb, Wl0, bl0, Wr0,
                                                      nullptr, hb, N);
    agg_kernel<<<aggBlocks, 256, 0, stream>>>(hb, rp, ssrc, agg, N);
    lin_kernel<false, true><<<1024, 256, 0, stream>>>(agg, hb, Wl1, bl1, Wr1,
                                                      out, nullptr, N);
}

// Round 8
// 199.667 us; speedup vs baseline: 1.5545x; 1.3560x over previous
//
#include <hip/hip_runtime.h>

#define N_NODES 50000
#define D 64
#define BKT_SHIFT 10
#define BKT_NODES 1024
#define NBKT ((N_NODES + BKT_NODES - 1) / BKT_NODES)   // 49 buckets
#define CAP 18432      // per-bucket edge capacity (mean 16384, sigma ~127 -> +16 sigma)
#define GPAD 32        // gcur padding: one counter per 128B line
#define XBLOCKS ((N_NODES * D / 4) / 256)               // 3125

typedef __attribute__((ext_vector_type(4))) float f4;
typedef __attribute__((ext_vector_type(4))) unsigned uv4;
typedef __attribute__((ext_vector_type(4))) unsigned short us4;
typedef __attribute__((ext_vector_type(8))) short bf16x8;
typedef __attribute__((ext_vector_type(4))) float f32x4;

// f32 -> bf16 round-to-nearest-even
static __device__ __forceinline__ unsigned short f2bf(float f) {
    unsigned u = __builtin_bit_cast(unsigned, f);
    unsigned r = (u + 0x7fffu + ((u >> 16) & 1u)) >> 16;
    return (unsigned short)r;
}

// int64-vs-int32 probe, inlined per wave
static __device__ __forceinline__ int detect_is64(const unsigned* __restrict__ ei32) {
    int lane = threadIdx.x & 63;
    unsigned v = (lane < 32) ? ei32[2 * lane + 1] : 0u;
    return (__ballot(v != 0u) == 0ull) ? 1 : 0;
}

// load 4 edges (src,dst) starting at `base`; returns count (<=4)
static __device__ __forceinline__ int load_edges4(const unsigned* __restrict__ ei32,
                                                  int is64, int E, int base,
                                                  int* s, int* d) {
    if (base + 3 < E) {
        if (is64) {
            uv4 sa = *(const uv4*)&ei32[2 * base];
            uv4 sb = *(const uv4*)&ei32[2 * base + 4];
            uv4 da = *(const uv4*)&ei32[2 * (E + base)];
            uv4 db = *(const uv4*)&ei32[2 * (E + base) + 4];
            s[0] = (int)sa[0]; s[1] = (int)sa[2]; s[2] = (int)sb[0]; s[3] = (int)sb[2];
            d[0] = (int)da[0]; d[1] = (int)da[2]; d[2] = (int)db[0]; d[3] = (int)db[2];
        } else {
            uv4 sa = *(const uv4*)&ei32[base];
            uv4 da = *(const uv4*)&ei32[E + base];
            s[0] = (int)sa[0]; s[1] = (int)sa[1]; s[2] = (int)sa[2]; s[3] = (int)sa[3];
            d[0] = (int)da[0]; d[1] = (int)da[1]; d[2] = (int)da[2]; d[3] = (int)da[3];
        }
        return 4;
    }
    int c = 0;
    for (int e = base; e < E && e < base + 4; ++e, ++c) {
        s[c] = is64 ? (int)ei32[2 * e] : (int)ei32[e];
        d[c] = is64 ? (int)ei32[2 * (E + e)] : (int)ei32[E + e];
    }
    return c;
}

// ---------------------------------------------------------------------------
// 0. fused setup: x->bf16 table, 4x W->bf16, gcur init (strided bases)
// ---------------------------------------------------------------------------
__global__ __launch_bounds__(256) void cvt_all(const float* __restrict__ x,
                                               unsigned short* __restrict__ xb,
                                               const float* __restrict__ Wl0,
                                               const float* __restrict__ Wr0,
                                               const float* __restrict__ Wl1,
                                               const float* __restrict__ Wr1,
                                               unsigned short* __restrict__ Wlb0,
                                               unsigned short* __restrict__ Wrb0,
                                               unsigned short* __restrict__ Wlb1,
                                               unsigned short* __restrict__ Wrb1,
                                               int* __restrict__ gcur) {
    int b = blockIdx.x, tid = threadIdx.x;
    if (b < XBLOCKS) {
        int i = (b * 256 + tid) * 4;   // exact: N*D multiple of 1024
        f4 v = *(const f4*)&x[i];
        us4 o;
        o[0] = f2bf(v[0]); o[1] = f2bf(v[1]); o[2] = f2bf(v[2]); o[3] = f2bf(v[3]);
        *(us4*)&xb[i] = o;
    } else if (b < XBLOCKS + 4) {
        int w = b - XBLOCKS;
        const float* src = (w == 0) ? Wl0 : (w == 1) ? Wr0 : (w == 2) ? Wl1 : Wr1;
        unsigned short* dst = (w == 0) ? Wlb0 : (w == 1) ? Wrb0 : (w == 2) ? Wlb1 : Wrb1;
        for (int i = tid * 4; i < 64 * 64; i += 1024) {
            f4 v = *(const f4*)&src[i];
            us4 o;
            o[0] = f2bf(v[0]); o[1] = f2bf(v[1]); o[2] = f2bf(v[2]); o[3] = f2bf(v[3]);
            *(us4*)&dst[i] = o;
        }
    } else {
        if (tid < NBKT) gcur[tid * GPAD] = tid * CAP;
    }
}

// ---------------------------------------------------------------------------
// 1. bin: group edges into fixed-capacity per-bucket regions. Per-block LDS
//    count -> one padded global atomic per bucket -> packed (dstLocal<<16|src)
//    into block-private chunks.
// ---------------------------------------------------------------------------
__global__ __launch_bounds__(256) void bin_kernel(const unsigned* __restrict__ ei32,
                                                  int E, int* __restrict__ gcur,
                                                  unsigned* __restrict__ binned) {
    __shared__ int bc[NBKT];
    __shared__ int boff[NBKT];
    int tid = threadIdx.x;
    for (int j = tid; j < NBKT; j += 256) bc[j] = 0;
    __syncthreads();
    int is64 = detect_is64(ei32);
    int base = (blockIdx.x * 256 + tid) * 4;
    int s[4], d[4];
    int c = 0;
    if (base < E) c = load_edges4(ei32, is64, E, base, s, d);
    for (int t = 0; t < c; ++t) atomicAdd(&bc[d[t] >> BKT_SHIFT], 1);
    __syncthreads();
    for (int j = tid; j < NBKT; j += 256) {
        int v = bc[j];
        boff[j] = v ? atomicAdd(&gcur[j * GPAD], v) : 0;   // absolute (seeded j*CAP)
        bc[j] = 0;
    }
    __syncthreads();
    for (int t = 0; t < c; ++t) {
        int bkt = d[t] >> BKT_SHIFT;
        int pos = boff[bkt] + atomicAdd(&bc[bkt], 1);
        if (pos < (bkt + 1) * CAP)   // overflow guard (16-sigma margin)
            binned[pos] = ((unsigned)(d[t] & (BKT_NODES - 1)) << 16) | (unsigned)s[t];
    }
}

// ---------------------------------------------------------------------------
// 2. build: one block per bucket. LDS node histogram, LDS scan, write
//    (beg,deg) pairs, scatter ssrc (ushort) within the bucket's window.
// ---------------------------------------------------------------------------
__global__ __launch_bounds__(256) void build_kernel(const unsigned* __restrict__ binned,
                                                    const int* __restrict__ gcur,
                                                    int2* __restrict__ rp2,
                                                    unsigned short* __restrict__ ssrc, int n) {
    __shared__ int nc[BKT_NODES];
    __shared__ int wpart[4];
    int b = blockIdx.x;
    int tid = threadIdx.x;
    int ebase = b * CAP;
    int eend = gcur[b * GPAD];
    if (eend > (b + 1) * CAP) eend = (b + 1) * CAP;
    for (int j = tid; j < BKT_NODES; j += 256) nc[j] = 0;
    __syncthreads();
    for (int i = ebase + tid; i < eend; i += 256)
        atomicAdd(&nc[binned[i] >> 16], 1);
    __syncthreads();
    int v[4]; int ts = 0;
#pragma unroll
    for (int i = 0; i < 4; ++i) { v[i] = nc[tid * 4 + i]; ts += v[i]; }
    int lane = tid & 63, wv = tid >> 6;
    int incl = ts;
#pragma unroll
    for (int off = 1; off < 64; off <<= 1) {
        int t = __shfl_up(incl, off);
        if (lane >= off) incl += t;
    }
    if (lane == 63) wpart[wv] = incl;
    __syncthreads();
    int wb = 0;
    for (int w2 = 0; w2 < wv; ++w2) wb += wpart[w2];
    int run = ebase + wb + incl - ts;
#pragma unroll
    for (int i = 0; i < 4; ++i) {
        int node = b * BKT_NODES + tid * 4 + i;
        nc[tid * 4 + i] = run;
        if (node < n) rp2[node] = make_int2(run, v[i]);
        run += v[i];
    }
    __syncthreads();
    for (int i = ebase + tid; i < eend; i += 256) {
        unsigned u = binned[i];
        int pos = atomicAdd(&nc[u >> 16], 1);
        ssrc[pos] = (unsigned short)(u & 0xffffu);
    }
}

// ---------------------------------------------------------------------------
// 3. aggregation (bf16 rows [N][64]) -> bf16 mean rows. wave per node.
//    lane = (slot r 0..7, chunk c 0..7); 16B bf16x8 loads, 16 edges in
//    flight; shfl_xor reduce over r.
// ---------------------------------------------------------------------------
__global__ __launch_bounds__(256) void agg_kernel(const unsigned short* __restrict__ xb,
                                                  const int2* __restrict__ rp2,
                                                  const unsigned short* __restrict__ ssrc,
                                                  unsigned short* __restrict__ aggb, int n) {
    int gw = (blockIdx.x * 256 + threadIdx.x) >> 6;
    if (gw >= n) return;
    int lane = threadIdx.x & 63;
    int r = lane >> 3;   // edge slot 0..7
    int c = lane & 7;    // bf16x8 chunk 0..7
    int2 bd = rp2[gw];
    int beg = bd.x, end = bd.x + bd.y;
    float acc[8] = {0.f, 0.f, 0.f, 0.f, 0.f, 0.f, 0.f, 0.f};
    int e = beg + r;
    for (; e + 8 < end; e += 16) {
        int s0 = ssrc[e];
        int s1 = ssrc[e + 8];
        uv4 v0 = *(const uv4*)(xb + (size_t)s0 * 64 + c * 8);
        uv4 v1 = *(const uv4*)(xb + (size_t)s1 * 64 + c * 8);
#pragma unroll
        for (int q = 0; q < 4; ++q) {
            unsigned w0 = v0[q], w1 = v1[q];
            acc[2 * q]     += __builtin_bit_cast(float, w0 << 16);
            acc[2 * q + 1] += __builtin_bit_cast(float, w0 & 0xffff0000u);
            acc[2 * q]     += __builtin_bit_cast(float, w1 << 16);
            acc[2 * q + 1] += __builtin_bit_cast(float, w1 & 0xffff0000u);
        }
    }
    if (e < end) {
        int s0 = ssrc[e];
        uv4 v0 = *(const uv4*)(xb + (size_t)s0 * 64 + c * 8);
#pragma unroll
        for (int q = 0; q < 4; ++q) {
            unsigned w0 = v0[q];
            acc[2 * q]     += __builtin_bit_cast(float, w0 << 16);
            acc[2 * q + 1] += __builtin_bit_cast(float, w0 & 0xffff0000u);
        }
    }
#pragma unroll
    for (int j = 0; j < 8; ++j) {
        float t = acc[j];
        t += __shfl_xor(t, 8);
        t += __shfl_xor(t, 16);
        t += __shfl_xor(t, 32);
        acc[j] = t;
    }
    if (r == 0) {
        int deg = bd.y;
        float inv = 1.0f / (float)(deg > 1 ? deg : 1);
        uv4 pk;
#pragma unroll
        for (int q = 0; q < 4; ++q)
            pk[q] = (unsigned)f2bf(acc[2 * q] * inv) |
                    ((unsigned)f2bf(acc[2 * q + 1] * inv) << 16);
        *(uv4*)&aggb[(size_t)gw * 64 + c * 8] = pk;
    }
}

// ---------------------------------------------------------------------------
// 4. linear via MFMA: out[n][o] = agg[n].Wl[o] + x[n].Wr[o] + bl[o] (+relu)
//    One wave = 16 nodes x 64 outputs = 4 o-tiles x 4 mfma_f32_16x16x32_bf16.
//    A-frags: contiguous 16B rows of aggb/xb (row=lane&15, k=(lane>>4)*8+j).
//    B-frags: contiguous 16B rows of bf16 W ([o][k] row-major = B^T pattern).
//    Bias as C-init. D: col=lane&15 (o), row=(lane>>4)*4+reg (node).
// ---------------------------------------------------------------------------
template <bool RELU, bool LAST>
__global__ __launch_bounds__(256) void lin_mfma(const unsigned short* __restrict__ aggb,
                                                const unsigned short* __restrict__ xb,
                                                const unsigned short* __restrict__ Wlb,
                                                const float* __restrict__ bl,
                                                const unsigned short* __restrict__ Wrb,
                                                float* __restrict__ out,
                                                unsigned short* __restrict__ ob, int n) {
    int gw = (blockIdx.x * 256 + threadIdx.x) >> 6;
    int nb = gw * 16;
    if (nb >= n) return;
    int lane = threadIdx.x & 63;
    int row = lane & 15;
    int half = lane >> 4;
    int koff = half * 8;
    bf16x8 a0 = *(const bf16x8*)&aggb[(size_t)(nb + row) * 64 + koff];
    bf16x8 a1 = *(const bf16x8*)&aggb[(size_t)(nb + row) * 64 + 32 + koff];
    bf16x8 x0 = *(const bf16x8*)&xb[(size_t)(nb + row) * 64 + koff];
    bf16x8 x1 = *(const bf16x8*)&xb[(size_t)(nb + row) * 64 + 32 + koff];
    f32x4 acc[4];
#pragma unroll
    for (int ot = 0; ot < 4; ++ot) {
        int o = ot * 16 + row;
        float bv = bl[o];
        acc[ot] = (f32x4){bv, bv, bv, bv};
        bf16x8 wl0 = *(const bf16x8*)&Wlb[(size_t)o * 64 + koff];
        bf16x8 wl1 = *(const bf16x8*)&Wlb[(size_t)o * 64 + 32 + koff];
        bf16x8 wr0 = *(const bf16x8*)&Wrb[(size_t)o * 64 + koff];
        bf16x8 wr1 = *(const bf16x8*)&Wrb[(size_t)o * 64 + 32 + koff];
        acc[ot] = __builtin_amdgcn_mfma_f32_16x16x32_bf16(a0, wl0, acc[ot], 0, 0, 0);
        acc[ot] = __builtin_amdgcn_mfma_f32_16x16x32_bf16(a1, wl1, acc[ot], 0, 0, 0);
        acc[ot] = __builtin_amdgcn_mfma_f32_16x16x32_bf16(x0, wr0, acc[ot], 0, 0, 0);
        acc[ot] = __builtin_amdgcn_mfma_f32_16x16x32_bf16(x1, wr1, acc[ot], 0, 0, 0);
    }
#pragma unroll
    for (int ot = 0; ot < 4; ++ot) {
        int o = ot * 16 + row;
#pragma unroll
        for (int r = 0; r < 4; ++r) {
            float v = acc[ot][r];
            if (RELU) v = fmaxf(v, 0.f);
            int node = nb + half * 4 + r;
            if (LAST) out[(size_t)node * 64 + o] = v;
            else      ob[(size_t)node * 64 + o] = f2bf(v);
        }
    }
}

// ---------------------------------------------------------------------------
extern "C" void kernel_launch(void* const* d_in, const int* in_sizes, int n_in,
                              void* d_out, int out_size, void* d_ws, size_t ws_size,
                              hipStream_t stream) {
    const float* x      = (const float*)d_in[0];
    const unsigned* ei  = (const unsigned*)d_in[1];
    const float* Wl0    = (const float*)d_in[2];
    const float* bl0    = (const float*)d_in[3];
    const float* Wr0    = (const float*)d_in[4];
    const float* Wl1    = (const float*)d_in[5];
    const float* bl1    = (const float*)d_in[6];
    const float* Wr1    = (const float*)d_in[7];
    float* out          = (float*)d_out;

    const int N = N_NODES;
    const int E = in_sizes[1] / 2;

    char* w = (char*)d_ws;
    auto take = [&](size_t bytes) {
        char* p = w;
        w += (bytes + 255) & ~(size_t)255;
        return p;
    };
    int*            gcur   = (int*)take((size_t)NBKT * GPAD * sizeof(int));
    unsigned*       binned = (unsigned*)take((size_t)NBKT * CAP * sizeof(unsigned));
    int2*           rp2    = (int2*)take((size_t)N * sizeof(int2));
    unsigned short* ssrc   = (unsigned short*)take((size_t)NBKT * CAP * sizeof(unsigned short));
    unsigned short* xb     = (unsigned short*)take((size_t)N * D * sizeof(unsigned short));
    unsigned short* hb     = (unsigned short*)take((size_t)N * D * sizeof(unsigned short));
    unsigned short* aggb   = (unsigned short*)take((size_t)N * D * sizeof(unsigned short));
    unsigned short* Wlb0   = (unsigned short*)take((size_t)D * D * sizeof(unsigned short));
    unsigned short* Wrb0   = (unsigned short*)take((size_t)D * D * sizeof(unsigned short));
    unsigned short* Wlb1   = (unsigned short*)take((size_t)D * D * sizeof(unsigned short));
    unsigned short* Wrb1   = (unsigned short*)take((size_t)D * D * sizeof(unsigned short));

    cvt_all<<<XBLOCKS + 5, 256, 0, stream>>>(x, xb, Wl0, Wr0, Wl1, Wr1,
                                             Wlb0, Wrb0, Wlb1, Wrb1, gcur);
    int edgeBlocks = (E + 1023) / 1024;   // 4 edges/thread
    bin_kernel<<<edgeBlocks, 256, 0, stream>>>(ei, E, gcur, binned);
    build_kernel<<<NBKT, 256, 0, stream>>>(binned, gcur, rp2, ssrc, N);

    int aggBlocks = (N * 64 + 255) / 256;       // one wave per node
    int linBlocks = ((N + 15) / 16 + 3) / 4;    // one wave per 16 nodes
    agg_kernel<<<aggBlocks, 256, 0, stream>>>(xb, rp2, ssrc, aggb, N);
    lin_mfma<true, false><<<linBlocks, 256, 0, stream>>>(aggb, xb, Wlb0, bl0, Wrb0,
                                                         nullptr, hb, N);
    agg_kernel<<<aggBlocks, 256, 0, stream>>>(hb, rp2, ssrc, aggb, N);
    lin_mfma<false, true><<<linBlocks, 256, 0, stream>>>(aggb, hb, Wlb1, bl1, Wrb1,
                                                         out, nullptr, N);
}

// Round 10
// 169.656 us; speedup vs baseline: 1.8294x; 1.1769x over previous
//
#include <hip/hip_runtime.h>

#define N_NODES 50000
#define D 64
#define BKT_SHIFT 10
#define BKT_NODES 1024
#define NBKT ((N_NODES + BKT_NODES - 1) / BKT_NODES)   // 49 buckets
#define CAP 18432      // per-bucket edge capacity (mean 16327, +16 sigma)
#define GPAD 32        // gcur padding: one counter per 128B line
#define XBLOCKS ((N_NODES * D / 4) / 256)               // 3125

typedef __attribute__((ext_vector_type(4))) float f4;
typedef __attribute__((ext_vector_type(4))) unsigned uv4;
typedef __attribute__((ext_vector_type(4))) unsigned short us4;
typedef __attribute__((ext_vector_type(8))) short bf16x8;
typedef __attribute__((ext_vector_type(4))) float f32x4;

// f32 -> bf16 round-to-nearest-even
static __device__ __forceinline__ unsigned short f2bf(float f) {
    unsigned u = __builtin_bit_cast(unsigned, f);
    unsigned r = (u + 0x7fffu + ((u >> 16) & 1u)) >> 16;
    return (unsigned short)r;
}
static __device__ __forceinline__ float bflo(unsigned w) {
    return __builtin_bit_cast(float, w << 16);
}
static __device__ __forceinline__ float bfhi(unsigned w) {
    return __builtin_bit_cast(float, w & 0xffff0000u);
}

// int64-vs-int32 probe, inlined per wave
static __device__ __forceinline__ int detect_is64(const unsigned* __restrict__ ei32) {
    int lane = threadIdx.x & 63;
    unsigned v = (lane < 32) ? ei32[2 * lane + 1] : 0u;
    return (__ballot(v != 0u) == 0ull) ? 1 : 0;
}

// load up to 4 edges (src,dst) starting at `base`; returns count (<=4)
static __device__ __forceinline__ int load_edges4(const unsigned* __restrict__ ei32,
                                                  int is64, int E, int base,
                                                  int* s, int* d) {
    if (base + 3 < E) {
        if (is64) {
            uv4 sa = *(const uv4*)&ei32[2 * base];
            uv4 sb = *(const uv4*)&ei32[2 * base + 4];
            uv4 da = *(const uv4*)&ei32[2 * (E + base)];
            uv4 db = *(const uv4*)&ei32[2 * (E + base) + 4];
            s[0] = (int)sa[0]; s[1] = (int)sa[2]; s[2] = (int)sb[0]; s[3] = (int)sb[2];
            d[0] = (int)da[0]; d[1] = (int)da[2]; d[2] = (int)db[0]; d[3] = (int)db[2];
        } else {
            uv4 sa = *(const uv4*)&ei32[base];
            uv4 da = *(const uv4*)&ei32[E + base];
            s[0] = (int)sa[0]; s[1] = (int)sa[1]; s[2] = (int)sa[2]; s[3] = (int)sa[3];
            d[0] = (int)da[0]; d[1] = (int)da[1]; d[2] = (int)da[2]; d[3] = (int)da[3];
        }
        return 4;
    }
    int c = 0;
    for (int e = base; e < E && e < base + 4; ++e, ++c) {
        s[c] = is64 ? (int)ei32[2 * e] : (int)ei32[e];
        d[c] = is64 ? (int)ei32[2 * (E + e)] : (int)ei32[E + e];
    }
    return c;
}

// ---------------------------------------------------------------------------
// 0. fused setup: x->bf16 table, 4x W->bf16, gcur init (strided bases)
// ---------------------------------------------------------------------------
__global__ __launch_bounds__(256) void cvt_all(const float* __restrict__ x,
                                               unsigned short* __restrict__ xb,
                                               const float* __restrict__ Wl0,
                                               const float* __restrict__ Wr0,
                                               const float* __restrict__ Wl1,
                                               const float* __restrict__ Wr1,
                                               unsigned short* __restrict__ Wlb0,
                                               unsigned short* __restrict__ Wrb0,
                                               unsigned short* __restrict__ Wlb1,
                                               unsigned short* __restrict__ Wrb1,
                                               int* __restrict__ gcur) {
    int b = blockIdx.x, tid = threadIdx.x;
    if (b < XBLOCKS) {
        int i = (b * 256 + tid) * 4;   // exact: N*D multiple of 1024
        f4 v = *(const f4*)&x[i];
        us4 o;
        o[0] = f2bf(v[0]); o[1] = f2bf(v[1]); o[2] = f2bf(v[2]); o[3] = f2bf(v[3]);
        *(us4*)&xb[i] = o;
    } else if (b < XBLOCKS + 4) {
        int w = b - XBLOCKS;
        const float* src = (w == 0) ? Wl0 : (w == 1) ? Wr0 : (w == 2) ? Wl1 : Wr1;
        unsigned short* dst = (w == 0) ? Wlb0 : (w == 1) ? Wrb0 : (w == 2) ? Wlb1 : Wrb1;
        for (int i = tid * 4; i < 64 * 64; i += 1024) {
            f4 v = *(const f4*)&src[i];
            us4 o;
            o[0] = f2bf(v[0]); o[1] = f2bf(v[1]); o[2] = f2bf(v[2]); o[3] = f2bf(v[3]);
            *(us4*)&dst[i] = o;
        }
    } else {
        if (tid < NBKT) gcur[tid * GPAD] = tid * CAP;
    }
}

// ---------------------------------------------------------------------------
// 1. bin: 8 edges/thread. Per-block LDS bucket count -> one padded global
//    atomic per bucket -> packed (dstLocal<<16|src) into block-private chunks.
// ---------------------------------------------------------------------------
__global__ __launch_bounds__(256) void bin_kernel(const unsigned* __restrict__ ei32,
                                                  int E, int* __restrict__ gcur,
                                                  unsigned* __restrict__ binned) {
    __shared__ int bc[NBKT];
    __shared__ int boff[NBKT];
    int tid = threadIdx.x;
    if (tid < NBKT) bc[tid] = 0;
    __syncthreads();
    int is64 = detect_is64(ei32);
    int base = (blockIdx.x * 256 + tid) * 8;
    int s[8], d[8];
    int c = 0;
    if (base < E) {
        c = load_edges4(ei32, is64, E, base, s, d);
        if (base + 4 < E) c += load_edges4(ei32, is64, E, base + 4, s + 4, d + 4);
    }
    for (int t = 0; t < c; ++t) atomicAdd(&bc[d[t] >> BKT_SHIFT], 1);
    __syncthreads();
    if (tid < NBKT) {
        int v = bc[tid];
        boff[tid] = v ? atomicAdd(&gcur[tid * GPAD], v) : 0;   // absolute (seeded tid*CAP)
        bc[tid] = 0;
    }
    __syncthreads();
    for (int t = 0; t < c; ++t) {
        int bkt = d[t] >> BKT_SHIFT;
        int pos = boff[bkt] + atomicAdd(&bc[bkt], 1);
        if (pos < (bkt + 1) * CAP)   // overflow guard (16-sigma margin)
            binned[pos] = ((unsigned)(d[t] & (BKT_NODES - 1)) << 16) | (unsigned)s[t];
    }
}

// ---------------------------------------------------------------------------
// 2. build: one 1024-thread block per bucket (1 node per thread).
//    LDS node histogram, shfl scan, write (beg,deg), scatter ssrc (ushort)
//    within the bucket's ~32KB window.
// ---------------------------------------------------------------------------
__global__ __launch_bounds__(1024) void build_kernel(const unsigned* __restrict__ binned,
                                                     const int* __restrict__ gcur,
                                                     int2* __restrict__ rp2,
                                                     unsigned short* __restrict__ ssrc, int n) {
    __shared__ int nc[BKT_NODES];
    __shared__ int wpart[16];
    int b = blockIdx.x;
    int tid = threadIdx.x;
    int ebase = b * CAP;
    int eend = gcur[b * GPAD];
    if (eend > ebase + CAP) eend = ebase + CAP;
    nc[tid] = 0;
    __syncthreads();
    for (int i = ebase + tid; i < eend; i += 1024)
        atomicAdd(&nc[binned[i] >> 16], 1);
    __syncthreads();
    int v = nc[tid];
    int lane = tid & 63, wv = tid >> 6;
    int incl = v;
#pragma unroll
    for (int off = 1; off < 64; off <<= 1) {
        int t = __shfl_up(incl, off);
        if (lane >= off) incl += t;
    }
    if (lane == 63) wpart[wv] = incl;
    __syncthreads();
    int pre = 0;
    for (int w2 = 0; w2 < wv; ++w2) pre += wpart[w2];
    int run = ebase + pre + incl - v;   // exclusive global position
    int node = b * BKT_NODES + tid;
    nc[tid] = run;                      // becomes the scatter cursor
    if (node < n) rp2[node] = make_int2(run, v);
    __syncthreads();
    for (int i = ebase + tid; i < eend; i += 1024) {
        unsigned u = binned[i];
        int pos = atomicAdd(&nc[u >> 16], 1);
        ssrc[pos] = (unsigned short)(u & 0xffffu);
    }
}

// ---------------------------------------------------------------------------
// 3. fused SAGE layer: mean-aggregate + MFMA linear + bias (+relu).
//    Wave = 16 nodes. Lane (half=lane>>4, row=lane&15) accumulates the
//    k-slice [half*8,+8) u [32+half*8,+8) of node nb+row over its CSR edges
//    in 16 f32 regs (2-edge unroll, 4x16B gathers in flight, no cross-lane
//    reduce), packs to bf16 — which IS the MFMA A-frag layout — then
//    4 o-tiles x 4 mfma_f32_16x16x32_bf16 with bias as C-init.
//    D mapping: o = ot*16 + (lane&15), node = nb + (lane>>4)*4 + reg.
// ---------------------------------------------------------------------------
template <bool RELU, bool LAST>
__global__ __launch_bounds__(256) void sage_fused(const unsigned short* __restrict__ xb,
                                                  const int2* __restrict__ rp2,
                                                  const unsigned short* __restrict__ ssrc,
                                                  const unsigned short* __restrict__ Wlb,
                                                  const float* __restrict__ bl,
                                                  const unsigned short* __restrict__ Wrb,
                                                  float* __restrict__ out,
                                                  unsigned short* __restrict__ ob, int n) {
    int gw = (blockIdx.x * 256 + threadIdx.x) >> 6;
    int nb = gw * 16;
    if (nb >= n) return;
    int lane = threadIdx.x & 63;
    int row = lane & 15;
    int half = lane >> 4;
    int koff = half * 8;
    int node = nb + row;
    int2 bd = rp2[node];
    int beg = bd.x, end = bd.x + bd.y;

    float acc[16];
#pragma unroll
    for (int j = 0; j < 16; ++j) acc[j] = 0.f;

    int e = beg;
    for (; e + 1 < end; e += 2) {
        int s0 = ssrc[e], s1 = ssrc[e + 1];
        uv4 v0 = *(const uv4*)(xb + (size_t)s0 * 64 + koff);
        uv4 v1 = *(const uv4*)(xb + (size_t)s0 * 64 + 32 + koff);
        uv4 v2 = *(const uv4*)(xb + (size_t)s1 * 64 + koff);
        uv4 v3 = *(const uv4*)(xb + (size_t)s1 * 64 + 32 + koff);
#pragma unroll
        for (int q = 0; q < 4; ++q) {
            acc[2 * q]     += bflo(v0[q]) + bflo(v2[q]);
            acc[2 * q + 1] += bfhi(v0[q]) + bfhi(v2[q]);
            acc[8 + 2 * q]     += bflo(v1[q]) + bflo(v3[q]);
            acc[8 + 2 * q + 1] += bfhi(v1[q]) + bfhi(v3[q]);
        }
    }
    if (e < end) {
        int s0 = ssrc[e];
        uv4 v0 = *(const uv4*)(xb + (size_t)s0 * 64 + koff);
        uv4 v1 = *(const uv4*)(xb + (size_t)s0 * 64 + 32 + koff);
#pragma unroll
        for (int q = 0; q < 4; ++q) {
            acc[2 * q]     += bflo(v0[q]);
            acc[2 * q + 1] += bfhi(v0[q]);
            acc[8 + 2 * q]     += bflo(v1[q]);
            acc[8 + 2 * q + 1] += bfhi(v1[q]);
        }
    }

    float inv = 1.0f / (float)(bd.y > 1 ? bd.y : 1);
    uv4 pa0, pa1;
#pragma unroll
    for (int q = 0; q < 4; ++q) {
        pa0[q] = (unsigned)f2bf(acc[2 * q] * inv) |
                 ((unsigned)f2bf(acc[2 * q + 1] * inv) << 16);
        pa1[q] = (unsigned)f2bf(acc[8 + 2 * q] * inv) |
                 ((unsigned)f2bf(acc[8 + 2 * q + 1] * inv) << 16);
    }
    bf16x8 a0 = __builtin_bit_cast(bf16x8, pa0);
    bf16x8 a1 = __builtin_bit_cast(bf16x8, pa1);
    bf16x8 x0 = *(const bf16x8*)&xb[(size_t)node * 64 + koff];
    bf16x8 x1 = *(const bf16x8*)&xb[(size_t)node * 64 + 32 + koff];

    f32x4 accd[4];
#pragma unroll
    for (int ot = 0; ot < 4; ++ot) {
        int o = ot * 16 + row;
        float bv = bl[o];
        accd[ot] = (f32x4){bv, bv, bv, bv};
        bf16x8 wl0 = *(const bf16x8*)&Wlb[(size_t)o * 64 + koff];
        bf16x8 wl1 = *(const bf16x8*)&Wlb[(size_t)o * 64 + 32 + koff];
        bf16x8 wr0 = *(const bf16x8*)&Wrb[(size_t)o * 64 + koff];
        bf16x8 wr1 = *(const bf16x8*)&Wrb[(size_t)o * 64 + 32 + koff];
        accd[ot] = __builtin_amdgcn_mfma_f32_16x16x32_bf16(a0, wl0, accd[ot], 0, 0, 0);
        accd[ot] = __builtin_amdgcn_mfma_f32_16x16x32_bf16(a1, wl1, accd[ot], 0, 0, 0);
        accd[ot] = __builtin_amdgcn_mfma_f32_16x16x32_bf16(x0, wr0, accd[ot], 0, 0, 0);
        accd[ot] = __builtin_amdgcn_mfma_f32_16x16x32_bf16(x1, wr1, accd[ot], 0, 0, 0);
    }
#pragma unroll
    for (int ot = 0; ot < 4; ++ot) {
        int o = ot * 16 + row;
#pragma unroll
        for (int r = 0; r < 4; ++r) {
            float v = accd[ot][r];
            if (RELU) v = fmaxf(v, 0.f);
            int nd = nb + half * 4 + r;
            if (LAST) out[(size_t)nd * 64 + o] = v;
            else      ob[(size_t)nd * 64 + o] = f2bf(v);
        }
    }
}

// ---------------------------------------------------------------------------
extern "C" void kernel_launch(void* const* d_in, const int* in_sizes, int n_in,
                              void* d_out, int out_size, void* d_ws, size_t ws_size,
                              hipStream_t stream) {
    const float* x      = (const float*)d_in[0];
    const unsigned* ei  = (const unsigned*)d_in[1];
    const float* Wl0    = (const float*)d_in[2];
    const float* bl0    = (const float*)d_in[3];
    const float* Wr0    = (const float*)d_in[4];
    const float* Wl1    = (const float*)d_in[5];
    const float* bl1    = (const float*)d_in[6];
    const float* Wr1    = (const float*)d_in[7];
    float* out          = (float*)d_out;

    const int N = N_NODES;
    const int E = in_sizes[1] / 2;

    char* w = (char*)d_ws;
    auto take = [&](size_t bytes) {
        char* p = w;
        w += (bytes + 255) & ~(size_t)255;
        return p;
    };
    int*            gcur   = (int*)take((size_t)NBKT * GPAD * sizeof(int));
    unsigned*       binned = (unsigned*)take((size_t)NBKT * CAP * sizeof(unsigned));
    int2*           rp2    = (int2*)take((size_t)N * sizeof(int2));
    unsigned short* ssrc   = (unsigned short*)take((size_t)NBKT * CAP * sizeof(unsigned short));
    unsigned short* xb     = (unsigned short*)take((size_t)N * D * sizeof(unsigned short));
    unsigned short* hb     = (unsigned short*)take((size_t)N * D * sizeof(unsigned short));
    unsigned short* Wlb0   = (unsigned short*)take((size_t)D * D * sizeof(unsigned short));
    unsigned short* Wrb0   = (unsigned short*)take((size_t)D * D * sizeof(unsigned short));
    unsigned short* Wlb1   = (unsigned short*)take((size_t)D * D * sizeof(unsigned short));
    unsigned short* Wrb1   = (unsigned short*)take((size_t)D * D * sizeof(unsigned short));

    cvt_all<<<XBLOCKS + 5, 256, 0, stream>>>(x, xb, Wl0, Wr0, Wl1, Wr1,
                                             Wlb0, Wrb0, Wlb1, Wrb1, gcur);
    int edgeBlocks = (E + 2047) / 2048;   // 8 edges/thread
    bin_kernel<<<edgeBlocks, 256, 0, stream>>>(ei, E, gcur, binned);
    build_kernel<<<NBKT, 1024, 0, stream>>>(binned, gcur, rp2, ssrc, N);

    int fusedBlocks = (N + 63) / 64;      // 64 nodes per 256-thread block
    sage_fused<true, false><<<fusedBlocks, 256, 0, stream>>>(xb, rp2, ssrc, Wlb0, bl0, Wrb0,
                                                             nullptr, hb, N);
    sage_fused<false, true><<<fusedBlocks, 256, 0, stream>>>(hb, rp2, ssrc, Wlb1, bl1, Wrb1,
                                                             out, nullptr, N);
}

// Round 11
// 164.496 us; speedup vs baseline: 1.8868x; 1.0314x over previous
//
#include <hip/hip_runtime.h>

#define N_NODES 50000
#define D 64
#define BKT_SHIFT 10
#define BKT_NODES 1024
#define NBKT ((N_NODES + BKT_NODES - 1) / BKT_NODES)   // 49 buckets
#define CAP 18432      // per-bucket edge capacity (mean 16327, +16 sigma)
#define GPAD 32        // gcur padding: one counter per 128B line
#define XBLOCKS ((N_NODES * D / 4) / 256)               // 3125

typedef __attribute__((ext_vector_type(4))) float f4;
typedef __attribute__((ext_vector_type(4))) unsigned uv4;
typedef __attribute__((ext_vector_type(4))) unsigned short us4;
typedef __attribute__((ext_vector_type(8))) short bf16x8;
typedef __attribute__((ext_vector_type(4))) float f32x4;

// f32 -> bf16 round-to-nearest-even
static __device__ __forceinline__ unsigned short f2bf(float f) {
    unsigned u = __builtin_bit_cast(unsigned, f);
    unsigned r = (u + 0x7fffu + ((u >> 16) & 1u)) >> 16;
    return (unsigned short)r;
}
static __device__ __forceinline__ float bflo(unsigned w) {
    return __builtin_bit_cast(float, w << 16);
}
static __device__ __forceinline__ float bfhi(unsigned w) {
    return __builtin_bit_cast(float, w & 0xffff0000u);
}

// int64-vs-int32 probe, inlined per wave
static __device__ __forceinline__ int detect_is64(const unsigned* __restrict__ ei32) {
    int lane = threadIdx.x & 63;
    unsigned v = (lane < 32) ? ei32[2 * lane + 1] : 0u;
    return (__ballot(v != 0u) == 0ull) ? 1 : 0;
}

// load up to 4 edges (src,dst) starting at `base`; returns count (<=4)
static __device__ __forceinline__ int load_edges4(const unsigned* __restrict__ ei32,
                                                  int is64, int E, int base,
                                                  int* s, int* d) {
    if (base + 3 < E) {
        if (is64) {
            uv4 sa = *(const uv4*)&ei32[2 * base];
            uv4 sb = *(const uv4*)&ei32[2 * base + 4];
            uv4 da = *(const uv4*)&ei32[2 * (E + base)];
            uv4 db = *(const uv4*)&ei32[2 * (E + base) + 4];
            s[0] = (int)sa[0]; s[1] = (int)sa[2]; s[2] = (int)sb[0]; s[3] = (int)sb[2];
            d[0] = (int)da[0]; d[1] = (int)da[2]; d[2] = (int)db[0]; d[3] = (int)db[2];
        } else {
            uv4 sa = *(const uv4*)&ei32[base];
            uv4 da = *(const uv4*)&ei32[E + base];
            s[0] = (int)sa[0]; s[1] = (int)sa[1]; s[2] = (int)sa[2]; s[3] = (int)sa[3];
            d[0] = (int)da[0]; d[1] = (int)da[1]; d[2] = (int)da[2]; d[3] = (int)da[3];
        }
        return 4;
    }
    int c = 0;
    for (int e = base; e < E && e < base + 4; ++e, ++c) {
        s[c] = is64 ? (int)ei32[2 * e] : (int)ei32[e];
        d[c] = is64 ? (int)ei32[2 * (E + e)] : (int)ei32[E + e];
    }
    return c;
}

// ---------------------------------------------------------------------------
// 0. fused setup: x->bf16 table, 4x W->bf16, gcur init (strided bases)
// ---------------------------------------------------------------------------
__global__ __launch_bounds__(256) void cvt_all(const float* __restrict__ x,
                                               unsigned short* __restrict__ xb,
                                               const float* __restrict__ Wl0,
                                               const float* __restrict__ Wr0,
                                               const float* __restrict__ Wl1,
                                               const float* __restrict__ Wr1,
                                               unsigned short* __restrict__ Wlb0,
                                               unsigned short* __restrict__ Wrb0,
                                               unsigned short* __restrict__ Wlb1,
                                               unsigned short* __restrict__ Wrb1,
                                               int* __restrict__ gcur) {
    int b = blockIdx.x, tid = threadIdx.x;
    if (b < XBLOCKS) {
        int i = (b * 256 + tid) * 4;   // exact: N*D multiple of 1024
        f4 v = *(const f4*)&x[i];
        us4 o;
        o[0] = f2bf(v[0]); o[1] = f2bf(v[1]); o[2] = f2bf(v[2]); o[3] = f2bf(v[3]);
        *(us4*)&xb[i] = o;
    } else if (b < XBLOCKS + 4) {
        int w = b - XBLOCKS;
        const float* src = (w == 0) ? Wl0 : (w == 1) ? Wr0 : (w == 2) ? Wl1 : Wr1;
        unsigned short* dst = (w == 0) ? Wlb0 : (w == 1) ? Wrb0 : (w == 2) ? Wlb1 : Wrb1;
        for (int i = tid * 4; i < 64 * 64; i += 1024) {
            f4 v = *(const f4*)&src[i];
            us4 o;
            o[0] = f2bf(v[0]); o[1] = f2bf(v[1]); o[2] = f2bf(v[2]); o[3] = f2bf(v[3]);
            *(us4*)&dst[i] = o;
        }
    } else {
        if (tid < NBKT) gcur[tid * GPAD] = tid * CAP;
    }
}

// ---------------------------------------------------------------------------
// 1. bin: 8 edges/thread. Per-block LDS bucket count -> one padded global
//    atomic per bucket -> packed (dstLocal<<16|src) into block-private chunks.
// ---------------------------------------------------------------------------
__global__ __launch_bounds__(256) void bin_kernel(const unsigned* __restrict__ ei32,
                                                  int E, int* __restrict__ gcur,
                                                  unsigned* __restrict__ binned) {
    __shared__ int bc[NBKT];
    __shared__ int boff[NBKT];
    int tid = threadIdx.x;
    if (tid < NBKT) bc[tid] = 0;
    __syncthreads();
    int is64 = detect_is64(ei32);
    int base = (blockIdx.x * 256 + tid) * 8;
    int s[8], d[8];
    int c = 0;
    if (base < E) {
        c = load_edges4(ei32, is64, E, base, s, d);
        if (base + 4 < E) c += load_edges4(ei32, is64, E, base + 4, s + 4, d + 4);
    }
    for (int t = 0; t < c; ++t) atomicAdd(&bc[d[t] >> BKT_SHIFT], 1);
    __syncthreads();
    if (tid < NBKT) {
        int v = bc[tid];
        boff[tid] = v ? atomicAdd(&gcur[tid * GPAD], v) : 0;   // absolute (seeded tid*CAP)
        bc[tid] = 0;
    }
    __syncthreads();
    for (int t = 0; t < c; ++t) {
        int bkt = d[t] >> BKT_SHIFT;
        int pos = boff[bkt] + atomicAdd(&bc[bkt], 1);
        if (pos < (bkt + 1) * CAP)   // overflow guard (16-sigma margin)
            binned[pos] = ((unsigned)(d[t] & (BKT_NODES - 1)) << 16) | (unsigned)s[t];
    }
}

// ---------------------------------------------------------------------------
// 2. build: one 1024-thread block per bucket (1 node per thread).
//    LDS node histogram, shfl scan, write (beg,deg), scatter ssrc (ushort)
//    within the bucket's ~32KB window.
// ---------------------------------------------------------------------------
__global__ __launch_bounds__(1024) void build_kernel(const unsigned* __restrict__ binned,
                                                     const int* __restrict__ gcur,
                                                     int2* __restrict__ rp2,
                                                     unsigned short* __restrict__ ssrc, int n) {
    __shared__ int nc[BKT_NODES];
    __shared__ int wpart[16];
    int b = blockIdx.x;
    int tid = threadIdx.x;
    int ebase = b * CAP;
    int eend = gcur[b * GPAD];
    if (eend > ebase + CAP) eend = ebase + CAP;
    nc[tid] = 0;
    __syncthreads();
    for (int i = ebase + tid; i < eend; i += 1024)
        atomicAdd(&nc[binned[i] >> 16], 1);
    __syncthreads();
    int v = nc[tid];
    int lane = tid & 63, wv = tid >> 6;
    int incl = v;
#pragma unroll
    for (int off = 1; off < 64; off <<= 1) {
        int t = __shfl_up(incl, off);
        if (lane >= off) incl += t;
    }
    if (lane == 63) wpart[wv] = incl;
    __syncthreads();
    int pre = 0;
    for (int w2 = 0; w2 < wv; ++w2) pre += wpart[w2];
    int run = ebase + pre + incl - v;   // exclusive global position
    int node = b * BKT_NODES + tid;
    nc[tid] = run;                      // becomes the scatter cursor
    if (node < n) rp2[node] = make_int2(run, v);
    __syncthreads();
    for (int i = ebase + tid; i < eend; i += 1024) {
        unsigned u = binned[i];
        int pos = atomicAdd(&nc[u >> 16], 1);
        ssrc[pos] = (unsigned short)(u & 0xffffu);
    }
}

// ---------------------------------------------------------------------------
// 3. fused SAGE layer, split-K: block = 256 threads = 4 waves = 16 nodes.
//    Each wave aggregates a QUARTER of every node's edge list into 16 f32
//    regs (lane = (half,row) k-slice, 2-edge unroll), partials combined via
//    conflict-free LDS (f4 lred[q][wave][lane]: consecutive lanes ->
//    consecutive 16B), then wave w computes o-tile w: 4x
//    mfma_f32_16x16x32_bf16 with bias as C-init.
//    4x more blocks than the monolithic version (3125 vs 782) -> ~20 waves/CU
//    of gather latency-hiding; serial chain per wave cut 4x.
//    D mapping: o = wv*16 + (lane&15), node = nb + (lane>>4)*4 + reg.
// ---------------------------------------------------------------------------
template <bool RELU, bool LAST>
__global__ __launch_bounds__(256) void sage_fused(const unsigned short* __restrict__ xb,
                                                  const int2* __restrict__ rp2,
                                                  const unsigned short* __restrict__ ssrc,
                                                  const unsigned short* __restrict__ Wlb,
                                                  const float* __restrict__ bl,
                                                  const unsigned short* __restrict__ Wrb,
                                                  float* __restrict__ out,
                                                  unsigned short* __restrict__ ob, int n) {
    __shared__ f4 lred[4][4][64];   // [q][wave][lane] -> lane-contiguous 16B
    int tid = threadIdx.x;
    int wv = tid >> 6;
    int lane = tid & 63;
    int nb = blockIdx.x * 16;       // grid is exact: N % 16 == 0
    int row = lane & 15;
    int half = lane >> 4;
    int koff = half * 8;
    int node = nb + row;
    int2 bd = rp2[node];
    int deg = bd.y;
    int chunk = (deg + 3) >> 2;     // this wave's share of the edge list
    int beg = bd.x + wv * chunk;
    int end = bd.x + deg;
    if (end > beg + chunk) end = beg + chunk;

    f4 acc4[4];
#pragma unroll
    for (int q = 0; q < 4; ++q) acc4[q] = (f4){0.f, 0.f, 0.f, 0.f};

    int e = beg;
    for (; e + 1 < end; e += 2) {
        int s0 = ssrc[e], s1 = ssrc[e + 1];
        uv4 v0 = *(const uv4*)(xb + (size_t)s0 * 64 + koff);
        uv4 v1 = *(const uv4*)(xb + (size_t)s0 * 64 + 32 + koff);
        uv4 v2 = *(const uv4*)(xb + (size_t)s1 * 64 + koff);
        uv4 v3 = *(const uv4*)(xb + (size_t)s1 * 64 + 32 + koff);
#pragma unroll
        for (int q = 0; q < 2; ++q) {
            acc4[q][0] += bflo(v0[2 * q])     + bflo(v2[2 * q]);
            acc4[q][1] += bfhi(v0[2 * q])     + bfhi(v2[2 * q]);
            acc4[q][2] += bflo(v0[2 * q + 1]) + bflo(v2[2 * q + 1]);
            acc4[q][3] += bfhi(v0[2 * q + 1]) + bfhi(v2[2 * q + 1]);
            acc4[2 + q][0] += bflo(v1[2 * q])     + bflo(v3[2 * q]);
            acc4[2 + q][1] += bfhi(v1[2 * q])     + bfhi(v3[2 * q]);
            acc4[2 + q][2] += bflo(v1[2 * q + 1]) + bflo(v3[2 * q + 1]);
            acc4[2 + q][3] += bfhi(v1[2 * q + 1]) + bfhi(v3[2 * q + 1]);
        }
    }
    if (e < end) {
        int s0 = ssrc[e];
        uv4 v0 = *(const uv4*)(xb + (size_t)s0 * 64 + koff);
        uv4 v1 = *(const uv4*)(xb + (size_t)s0 * 64 + 32 + koff);
#pragma unroll
        for (int q = 0; q < 2; ++q) {
            acc4[q][0] += bflo(v0[2 * q]);
            acc4[q][1] += bfhi(v0[2 * q]);
            acc4[q][2] += bflo(v0[2 * q + 1]);
            acc4[q][3] += bfhi(v0[2 * q + 1]);
            acc4[2 + q][0] += bflo(v1[2 * q]);
            acc4[2 + q][1] += bfhi(v1[2 * q]);
            acc4[2 + q][2] += bflo(v1[2 * q + 1]);
            acc4[2 + q][3] += bfhi(v1[2 * q + 1]);
        }
    }

    // cross-wave combine: write own partial, read the other three
#pragma unroll
    for (int q = 0; q < 4; ++q) lred[q][wv][lane] = acc4[q];
    __syncthreads();
#pragma unroll
    for (int w2 = 0; w2 < 4; ++w2) {
        if (w2 == wv) continue;
#pragma unroll
        for (int q = 0; q < 4; ++q) acc4[q] += lred[q][w2][lane];
    }

    float inv = 1.0f / (float)(deg > 1 ? deg : 1);
    uv4 pa0, pa1;
#pragma unroll
    for (int q = 0; q < 2; ++q) {
        pa0[2 * q]     = (unsigned)f2bf(acc4[q][0] * inv) |
                         ((unsigned)f2bf(acc4[q][1] * inv) << 16);
        pa0[2 * q + 1] = (unsigned)f2bf(acc4[q][2] * inv) |
                         ((unsigned)f2bf(acc4[q][3] * inv) << 16);
        pa1[2 * q]     = (unsigned)f2bf(acc4[2 + q][0] * inv) |
                         ((unsigned)f2bf(acc4[2 + q][1] * inv) << 16);
        pa1[2 * q + 1] = (unsigned)f2bf(acc4[2 + q][2] * inv) |
                         ((unsigned)f2bf(acc4[2 + q][3] * inv) << 16);
    }
    bf16x8 a0 = __builtin_bit_cast(bf16x8, pa0);
    bf16x8 a1 = __builtin_bit_cast(bf16x8, pa1);
    bf16x8 x0 = *(const bf16x8*)&xb[(size_t)node * 64 + koff];
    bf16x8 x1 = *(const bf16x8*)&xb[(size_t)node * 64 + 32 + koff];

    // this wave's o-tile
    int o = wv * 16 + row;
    float bv = bl[o];
    f32x4 accd = (f32x4){bv, bv, bv, bv};
    bf16x8 wl0 = *(const bf16x8*)&Wlb[(size_t)o * 64 + koff];
    bf16x8 wl1 = *(const bf16x8*)&Wlb[(size_t)o * 64 + 32 + koff];
    bf16x8 wr0 = *(const bf16x8*)&Wrb[(size_t)o * 64 + koff];
    bf16x8 wr1 = *(const bf16x8*)&Wrb[(size_t)o * 64 + 32 + koff];
    accd = __builtin_amdgcn_mfma_f32_16x16x32_bf16(a0, wl0, accd, 0, 0, 0);
    accd = __builtin_amdgcn_mfma_f32_16x16x32_bf16(a1, wl1, accd, 0, 0, 0);
    accd = __builtin_amdgcn_mfma_f32_16x16x32_bf16(x0, wr0, accd, 0, 0, 0);
    accd = __builtin_amdgcn_mfma_f32_16x16x32_bf16(x1, wr1, accd, 0, 0, 0);

#pragma unroll
    for (int r = 0; r < 4; ++r) {
        float v = accd[r];
        if (RELU) v = fmaxf(v, 0.f);
        int nd = nb + half * 4 + r;
        if (LAST) out[(size_t)nd * 64 + o] = v;
        else      ob[(size_t)nd * 64 + o] = f2bf(v);
    }
}

// ---------------------------------------------------------------------------
extern "C" void kernel_launch(void* const* d_in, const int* in_sizes, int n_in,
                              void* d_out, int out_size, void* d_ws, size_t ws_size,
                              hipStream_t stream) {
    const float* x      = (const float*)d_in[0];
    const unsigned* ei  = (const unsigned*)d_in[1];
    const float* Wl0    = (const float*)d_in[2];
    const float* bl0    = (const float*)d_in[3];
    const float* Wr0    = (const float*)d_in[4];
    const float* Wl1    = (const float*)d_in[5];
    const float* bl1    = (const float*)d_in[6];
    const float* Wr1    = (const float*)d_in[7];
    float* out          = (float*)d_out;

    const int N = N_NODES;
    const int E = in_sizes[1] / 2;

    char* w = (char*)d_ws;
    auto take = [&](size_t bytes) {
        char* p = w;
        w += (bytes + 255) & ~(size_t)255;
        return p;
    };
    int*            gcur   = (int*)take((size_t)NBKT * GPAD * sizeof(int));
    unsigned*       binned = (unsigned*)take((size_t)NBKT * CAP * sizeof(unsigned));
    int2*           rp2    = (int2*)take((size_t)N * sizeof(int2));
    unsigned short* ssrc   = (unsigned short*)take((size_t)NBKT * CAP * sizeof(unsigned short));
    unsigned short* xb     = (unsigned short*)take((size_t)N * D * sizeof(unsigned short));
    unsigned short* hb     = (unsigned short*)take((size_t)N * D * sizeof(unsigned short));
    unsigned short* Wlb0   = (unsigned short*)take((size_t)D * D * sizeof(unsigned short));
    unsigned short* Wrb0   = (unsigned short*)take((size_t)D * D * sizeof(unsigned short));
    unsigned short* Wlb1   = (unsigned short*)take((size_t)D * D * sizeof(unsigned short));
    unsigned short* Wrb1   = (unsigned short*)take((size_t)D * D * sizeof(unsigned short));

    cvt_all<<<XBLOCKS + 5, 256, 0, stream>>>(x, xb, Wl0, Wr0, Wl1, Wr1,
                                             Wlb0, Wrb0, Wlb1, Wrb1, gcur);
    int edgeBlocks = (E + 2047) / 2048;   // 8 edges/thread
    bin_kernel<<<edgeBlocks, 256, 0, stream>>>(ei, E, gcur, binned);
    build_kernel<<<NBKT, 1024, 0, stream>>>(binned, gcur, rp2, ssrc, N);

    int fusedBlocks = (N + 15) / 16;      // 16 nodes per 256-thread block
    sage_fused<true, false><<<fusedBlocks, 256, 0, stream>>>(xb, rp2, ssrc, Wlb0, bl0, Wrb0,
                                                             nullptr, hb, N);
    sage_fused<false, true><<<fusedBlocks, 256, 0, stream>>>(hb, rp2, ssrc, Wlb1, bl1, Wrb1,
                                                             out, nullptr, N);
}